// Round 3
// 443.490 us; speedup vs baseline: 1.0219x; 1.0219x over previous
//
#include <hip/hip_runtime.h>
#include <math.h>

// PatchNCE loss via bf16 MFMA, fully layer-batched: 4 dispatches total.
// stageA: zero loss + cast W->bf16 + corner-tile gather (LDS-staged, dense
//         128B corner-row reads) -> ftb (bf16, row-major [row][C])
// stageB: gemm1 MFMA + relu -> y1b        (all layers, flattened grid)
//         v2: 256x64 tile/block, 64x64 per wave: 16 MFMA / 8 loads (2:1)
// stageC: gemm2 MFMA + row L2-norm -> Fb  (bf16, row stride RS=max(C4,32))
//         v2: 2 m-frags per wave: 2*NF MFMA / (NF+2) loads
// stageD: NCE Gram MFMA + fused exp/LSE -> atomicAdd loss (1 atomic/block)
//         v2: 32 s-rows/block (a[2]): 16 MFMA / 10 loads, Fk re-reads halved
// MFMA 16x16x32 bf16: A/B frag: row=lane&15, k=(lane>>4)*8 (+8 contiguous);
// C/D: col=lane&15, row=(lane>>4)*4+reg.

#define BATCH 8
#define SS    512
#define MM    4096
#define M2    8192

typedef __attribute__((ext_vector_type(8))) short bf16x8;
typedef __attribute__((ext_vector_type(4))) float f32x4;

struct Args {
  const float* fq[4]; const float* fk[4]; const int* sid[4];
  const float* w1[4]; const float* b1[4]; const float* w2[4]; const float* b2[4];
  short* w1b[4]; short* w2b[4]; short* ftb[4]; short* y1b[4]; short* Fb[4];
  float* out;
};

static __device__ __forceinline__ short f2bf(float f) {
  union { float f; unsigned u; } v; v.f = f;
  unsigned r = (v.u + 0x7fffu + ((v.u >> 16) & 1u)) >> 16;   // RNE
  return (short)r;
}
static __device__ __forceinline__ float bf2f(short s) {
  union { unsigned u; float f; } v;
  v.u = ((unsigned)(unsigned short)s) << 16;
  return v.f;
}

// ---------------- stage A: zero + cast weights + corner gather --------------
// blocks 0..1919: gather. block=(side,b,8ch tile): l0:128, l1:256, l2:512,
// l3:1024 (cum 128,384,896,1920). blocks 1920..3619: weight cast.
// All sampled pixels lie in the 32x32 corner (sid<30, +dh/dw<=2 -> idx<=31).
__global__ __launch_bounds__(256) void stageA(Args A) {
  const int bx = blockIdx.x, tid = threadIdx.x;
  if (bx < 1920) {
    int l, idx;
    if (bx < 128)      { l = 0; idx = bx; }
    else if (bx < 384) { l = 1; idx = bx - 128; }
    else if (bx < 896) { l = 2; idx = bx - 384; }
    else               { l = 3; idx = bx - 896; }
    const int C = 64 << l, H = 256 >> l, HW = H * H;
    const int tile = idx & ((C >> 3) - 1);          // C/8 tiles
    const int b = (idx >> (3 + l)) & 7;
    const int side = idx >> (6 + l);
    const int ch0 = tile * 8;
    const float* feat = side ? A.fk[l] : A.fq[l];

    __shared__ short cor[8 * 1032];                 // 8 ch, stride 1032 shorts
    __shared__ int sidS[128];
    if (tid < 128) sidS[tid] = A.sid[l][tid];

    // phase 1: dense corner-row loads, cast to bf16 in LDS
    const int ch = tid >> 5, i = tid & 31;          // 8 ch x 32 rows
    const float* src = feat + (size_t)(b * C + ch0 + ch) * HW + (size_t)i * H;
    short* dst = &cor[ch * 1032 + i * 32];
#pragma unroll
    for (int j = 0; j < 8; ++j) {
      float4 v = *(const float4*)(src + 4 * j);
      short4 s;
      s.x = f2bf(v.x); s.y = f2bf(v.y); s.z = f2bf(v.z); s.w = f2bf(v.w);
      *(short4*)(dst + 4 * j) = s;
    }
    __syncthreads();

    // phase 2: 512 rows x 8 ch from LDS
    const int ch2 = tid & 7, r0 = tid >> 3;         // r0: 0..31
    const short* corch = &cor[ch2 * 1032];
    short* ftl = A.ftb[l];
#pragma unroll 4
    for (int jj = 0; jj < 16; ++jj) {
      const int sr = r0 + jj * 32;                  // 0..511
      const int s = sr >> 3, n = sr & 7;
      const int id2 = n < 4 ? n : n + 1;            // skip center of 3x3
      const int dh = id2 / 3, dw = id2 % 3;
      const int sh = sidS[2 * s], sw = sidS[2 * s + 1];
      const int p1 = (sh + dh) * 32 + sw + dw;
      const int p2 = (sh + 1) * 32 + sw + 1;
      const float d = bf2f(corch[p1]) - bf2f(corch[p2]);
      const int row = side * MM + b * SS + sr;
      ftl[(size_t)row * C + ch0 + ch2] = f2bf(d);
    }
  } else {
    const int cb = bx - 1920;
    int l, base;
    if (cb < 20)       { l = 0; base = cb; }
    else if (cb < 100) { l = 1; base = cb - 20; }
    else if (cb < 420) { l = 2; base = cb - 100; }
    else               { l = 3; base = cb - 420; }
    if (cb == 0 && tid == 0) A.out[0] = 0.0f;
    const int C = 64 << l;
    const int n1 = C * C, n2 = C * (C >> 2);
    const int i = base * 256 + tid;
    if (i < n1) A.w1b[l][i] = f2bf(A.w1[l][i]);
    else if (i < n1 + n2) A.w2b[l][i - n1] = f2bf(A.w2[l][i - n1]);
  }
}

// ---------------- stage B: Y = relu(ft @ W1^T + b1), all layers -------------
// v2: per layer (M2/256) m-tiles x (C/64) n-tiles: 32,64,128,256 blocks
// (cum 32,96,224,480). Each wave: 64 rows x 64 cols = a[4] x b[4] frags.
__global__ __launch_bounds__(256) void stageB(Args A) {
  const int bx = blockIdx.x, tid = threadIdx.x;
  int l, bl;
  if (bx < 32)       { l = 0; bl = bx; }
  else if (bx < 96)  { l = 1; bl = bx - 32; }
  else if (bx < 224) { l = 2; bl = bx - 96; }
  else               { l = 3; bl = bx - 224; }
  const int C = 64 << l;
  const int lane = tid & 63, w = tid >> 6;
  const int m0 = (bl & 31) * 256 + w * 64;          // wave's 64-row strip
  const int n0 = (bl >> 5) * 64;                    // block's 64-col strip
  const int l16 = lane & 15;
  const int q8 = (lane >> 4) * 8;
  f32x4 acc[4][4];
#pragma unroll
  for (int i = 0; i < 4; ++i)
#pragma unroll
    for (int j = 0; j < 4; ++j) acc[i][j] = (f32x4)(0.f);

  const short* Ap = A.ftb[l] + (size_t)(m0 + l16) * C + q8;
  const short* Wp = A.w1b[l] + (size_t)(n0 + l16) * C + q8;
  for (int k0 = 0; k0 < C; k0 += 32) {
    bf16x8 a[4], b[4];
#pragma unroll
    for (int mi = 0; mi < 4; ++mi)
      a[mi] = *(const bf16x8*)(Ap + (size_t)mi * 16 * C + k0);
#pragma unroll
    for (int ni = 0; ni < 4; ++ni)
      b[ni] = *(const bf16x8*)(Wp + (size_t)ni * 16 * C + k0);
#pragma unroll
    for (int mi = 0; mi < 4; ++mi)
#pragma unroll
      for (int ni = 0; ni < 4; ++ni)
        acc[mi][ni] = __builtin_amdgcn_mfma_f32_16x16x32_bf16(
            a[mi], b[ni], acc[mi][ni], 0, 0, 0);
  }
  const int rq = (lane >> 4) * 4;
  short* Y = A.y1b[l];
  const float* bias = A.b1[l];
#pragma unroll
  for (int ni = 0; ni < 4; ++ni) {
    const int n = n0 + ni * 16 + l16;
    const float bb = bias[n];
#pragma unroll
    for (int mi = 0; mi < 4; ++mi)
#pragma unroll
      for (int r = 0; r < 4; ++r) {
        const int m = m0 + mi * 16 + rq + r;
        Y[(size_t)m * C + n] = f2bf(fmaxf(acc[mi][ni][r] + bb, 0.f));
      }
  }
}

// ---------------- stage C: F = normalize(Y @ W2^T + b2), all layers ---------
// v2: each wave owns 32 rows (a[2] m-frags) x all C4 cols (NF b-frags).
template <int NF>
static __device__ __forceinline__ void g2body(
    const short* __restrict__ Yl, const short* __restrict__ Wl,
    const float* __restrict__ b2, short* __restrict__ F,
    int C, int RS, int m0, int lane) {
  const int l16 = lane & 15;
  const int q8 = (lane >> 4) * 8;
  f32x4 acc[2][NF];
#pragma unroll
  for (int mi = 0; mi < 2; ++mi)
#pragma unroll
    for (int f = 0; f < NF; ++f) acc[mi][f] = (f32x4)(0.f);
  const short* Ap = Yl + (size_t)(m0 + l16) * C + q8;
  const short* Wp = Wl + (size_t)l16 * C + q8;
  for (int k0 = 0; k0 < C; k0 += 32) {
    bf16x8 a[2];
#pragma unroll
    for (int mi = 0; mi < 2; ++mi)
      a[mi] = *(const bf16x8*)(Ap + (size_t)mi * 16 * C + k0);
#pragma unroll
    for (int f = 0; f < NF; ++f) {
      bf16x8 b = *(const bf16x8*)(Wp + (size_t)f * 16 * C + k0);
#pragma unroll
      for (int mi = 0; mi < 2; ++mi)
        acc[mi][f] = __builtin_amdgcn_mfma_f32_16x16x32_bf16(
            a[mi], b, acc[mi][f], 0, 0, 0);
    }
  }
  const int rq = (lane >> 4) * 4;
#pragma unroll
  for (int mi = 0; mi < 2; ++mi) {
    float ss[4] = {0.f, 0.f, 0.f, 0.f};
#pragma unroll
    for (int f = 0; f < NF; ++f) {
      const float bb = b2[f * 16 + l16];
#pragma unroll
      for (int r = 0; r < 4; ++r) {
        acc[mi][f][r] += bb;
        ss[r] += acc[mi][f][r] * acc[mi][f][r];
      }
    }
#pragma unroll
    for (int m = 1; m <= 8; m <<= 1)
#pragma unroll
      for (int r = 0; r < 4; ++r) ss[r] += __shfl_xor(ss[r], m, 64);
#pragma unroll
    for (int f = 0; f < NF; ++f)
#pragma unroll
      for (int r = 0; r < 4; ++r)
        F[(size_t)(m0 + mi * 16 + rq + r) * RS + f * 16 + l16] =
            f2bf(acc[mi][f][r] / (sqrtf(ss[r]) + 1e-7f));
    if (NF == 1) {  // C4==16 < RS==32: zero-pad cols 16..31
#pragma unroll
      for (int r = 0; r < 4; ++r)
        F[(size_t)(m0 + mi * 16 + rq + r) * RS + 16 + l16] = 0;
    }
  }
}

__global__ __launch_bounds__(256) void stageC(Args A) {
  const int bx = blockIdx.x, tid = threadIdx.x;
  const int l = bx >> 6, bl = bx & 63;              // 64 blocks/layer x 128 rows
  const int C = 64 << l, C4 = C >> 2;
  const int RS = C4 < 32 ? 32 : C4;
  const int lane = tid & 63, w = tid >> 6;
  const int m0 = bl * 128 + w * 32;
  if (l == 0)      g2body<1>(A.y1b[0], A.w2b[0], A.b2[0], A.Fb[0], C, RS, m0, lane);
  else if (l == 1) g2body<2>(A.y1b[1], A.w2b[1], A.b2[1], A.Fb[1], C, RS, m0, lane);
  else if (l == 2) g2body<4>(A.y1b[2], A.w2b[2], A.b2[2], A.Fb[2], C, RS, m0, lane);
  else             g2body<8>(A.y1b[3], A.w2b[3], A.b2[3], A.Fb[3], C, RS, m0, lane);
}

// ---------------- stage D: NCE Gram + fused exp/LSE, all layers -------------
// v2: block = 32 s-rows (a[2] frags); 4 waves each cover 128 t's (8 frags);
// LDS cross-wave reduce; one atomicAdd per block. 128 blocks/layer, 512 total.
__global__ __launch_bounds__(256) void stageD(Args A) {
  const int bx = blockIdx.x, tid = threadIdx.x;
  const int l = bx >> 7, rem = bx & 127;
  const int b = rem >> 4, sblk = rem & 15;
  const int C4 = (64 << l) >> 2;
  const int RS = C4 < 32 ? 32 : C4;
  const int lane = tid & 63, w = tid >> 6;
  const int l16 = lane & 15;
  const int q8 = (lane >> 4) * 8;
  const int rq = (lane >> 4) * 4;
  const int s0 = sblk * 32;
  const short* F = A.Fb[l];
  f32x4 acc[2][8];
#pragma unroll
  for (int si = 0; si < 2; ++si)
#pragma unroll
    for (int f = 0; f < 8; ++f) acc[si][f] = (f32x4)(0.f);
  const short* Fqp = F + (size_t)(b * SS + s0 + l16) * RS + q8;
  const short* Fkp = F + (size_t)(MM + b * SS + w * 128 + l16) * RS + q8;
  for (int k0 = 0; k0 < RS; k0 += 32) {
    bf16x8 a[2];
#pragma unroll
    for (int si = 0; si < 2; ++si)
      a[si] = *(const bf16x8*)(Fqp + (size_t)si * 16 * RS + k0);
#pragma unroll
    for (int f = 0; f < 8; ++f) {
      bf16x8 bb = *(const bf16x8*)(Fkp + (size_t)f * 16 * RS + k0);
#pragma unroll
      for (int si = 0; si < 2; ++si)
        acc[si][f] = __builtin_amdgcn_mfma_f32_16x16x32_bf16(
            a[si], bb, acc[si][f], 0, 0, 0);
    }
  }
  const float invtau = 1.0f / 0.07f;
  float rs[2][4], pos[2][4];
#pragma unroll
  for (int si = 0; si < 2; ++si)
#pragma unroll
    for (int r = 0; r < 4; ++r) { rs[si][r] = 0.f; pos[si][r] = 0.f; }
#pragma unroll
  for (int f = 0; f < 8; ++f) {
    const int t = w * 128 + f * 16 + l16;
#pragma unroll
    for (int si = 0; si < 2; ++si)
#pragma unroll
      for (int r = 0; r < 4; ++r) {
        const int s = s0 + si * 16 + rq + r;
        const float d = acc[si][f][r];
        if (t == s) pos[si][r] = d;
        else rs[si][r] += __expf((d - 1.f) * invtau);
      }
  }
#pragma unroll
  for (int m = 1; m <= 8; m <<= 1)
#pragma unroll
    for (int si = 0; si < 2; ++si)
#pragma unroll
      for (int r = 0; r < 4; ++r) {
        rs[si][r] += __shfl_xor(rs[si][r], m, 64);
        pos[si][r] += __shfl_xor(pos[si][r], m, 64);
      }
  __shared__ float rsS[4][32];
  __shared__ float posS[32];
  const int wd = sblk >> 2;   // wave whose t-range contains the diagonal
  if (l16 == 0) {
#pragma unroll
    for (int si = 0; si < 2; ++si)
#pragma unroll
      for (int r = 0; r < 4; ++r) rsS[w][si * 16 + rq + r] = rs[si][r];
    if (w == wd)
#pragma unroll
      for (int si = 0; si < 2; ++si)
#pragma unroll
        for (int r = 0; r < 4; ++r) posS[si * 16 + rq + r] = pos[si][r];
  }
  __syncthreads();
  if (tid < 32) {
    const float tot = rsS[0][tid] + rsS[1][tid] + rsS[2][tid] + rsS[3][tid];
    const float p = posS[tid];
    float v = logf(tot + __expf((p - 1.f) * invtau)) + invtau - p * invtau;
#pragma unroll
    for (int m = 1; m <= 16; m <<= 1) v += __shfl_xor(v, m, 64);
    if (tid == 0) atomicAdd(A.out, v * (1.0f / (float)MM));
  }
}

extern "C" void kernel_launch(void* const* d_in, const int* in_sizes, int n_in,
                              void* d_out, int out_size, void* d_ws, size_t ws_size,
                              hipStream_t stream) {
  short* ws = (short*)d_ws;
  // static workspace offsets (in shorts), all 16B-aligned
  static const size_t w1o[4] = {0, 4096, 20480, 86016};
  static const size_t w2o[4] = {348160, 349184, 353280, 369664};
  static const size_t fto[4] = {435200, 959488, 2008064, 4105216};
  static const size_t y1o[4] = {8299520, 8823808, 9872384, 11969536};
  static const size_t Fbo[4] = {16163840, 16425984, 16688128, 17212416};
  Args A;
  for (int l = 0; l < 4; ++l) {
    A.fq[l] = (const float*)d_in[7 * l + 0];
    A.fk[l] = (const float*)d_in[7 * l + 1];
    A.sid[l] = (const int*)d_in[7 * l + 2];
    A.w1[l] = (const float*)d_in[7 * l + 3];
    A.b1[l] = (const float*)d_in[7 * l + 4];
    A.w2[l] = (const float*)d_in[7 * l + 5];
    A.b2[l] = (const float*)d_in[7 * l + 6];
    A.w1b[l] = ws + w1o[l];
    A.w2b[l] = ws + w2o[l];
    A.ftb[l] = ws + fto[l];
    A.y1b[l] = ws + y1o[l];
    A.Fb[l] = ws + Fbo[l];
  }
  A.out = (float*)d_out;

  stageA<<<3620, 256, 0, stream>>>(A);
  stageB<<<480, 256, 0, stream>>>(A);
  stageC<<<256, 256, 0, stream>>>(A);
  stageD<<<512, 256, 0, stream>>>(A);
}